// Round 3
// baseline (1295.292 us; speedup 1.0000x reference)
//
#include <hip/hip_runtime.h>
#include <math.h>

#define NN 50000
#define NE 1600000
#define DIN 512
#define HH 128
#define EPSBN 1e-5f
#define NB 782        // ceil(NN/64) buckets of 64 nodes
#define NBP 1024      // padded bucket array
#define CAPE 4096     // per-bucket edge capacity (mean 2046, std ~45)

// ---------------- zero bucket counts + BN stat accumulators ----------------
__global__ void k_zero(int* __restrict__ bcnt, float* __restrict__ st) {
    int i = blockIdx.x * 256 + threadIdx.x;
    if (i < NBP) bcnt[i] = 0;
    if (i < 512) st[i] = 0.0f;
}

// ---------------- bucket count ----------------
__global__ void k_bcount(const int* __restrict__ dst, int* __restrict__ bcnt) {
    int e = blockIdx.x * 256 + threadIdx.x;
    if (e < NE) atomicAdd(&bcnt[dst[e] >> 6], 1);
}

// ---------------- bucket scan (1 block, 1024 threads) ----------------
__global__ __launch_bounds__(1024) void k_bscan(const int* __restrict__ bcnt,
                                                int* __restrict__ bbase,
                                                int* __restrict__ bcursor,
                                                int* __restrict__ rowptr) {
    __shared__ int ps[1024];
    int t = threadIdx.x;
    int v = (t < NB) ? bcnt[t] : 0;
    ps[t] = v;
    __syncthreads();
    for (int off = 1; off < 1024; off <<= 1) {
        int u = (t >= off) ? ps[t - off] : 0;
        __syncthreads();
        ps[t] += u;
        __syncthreads();
    }
    int ex = ps[t] - v;
    bbase[t] = ex;
    bcursor[t] = ex;
    if (t == 0) rowptr[NN] = NE;
}

// ---------------- scatter edges into bucket order (packed (dst&63)<<16 | src) ----------------
__global__ void k_bscatter(const int* __restrict__ src, const int* __restrict__ dst,
                           int* __restrict__ bcursor, int* __restrict__ packed) {
    int e = blockIdx.x * 256 + threadIdx.x;
    if (e < NE) {
        int s = src[e], d = dst[e];
        int pos = atomicAdd(&bcursor[d >> 6], 1);
        packed[pos] = ((d & 63) << 16) | s;   // src < 50000 < 2^16
    }
}

// ---------------- per-bucket CSR finalize: csr_src, rowptr, dinv ----------------
__global__ __launch_bounds__(256) void k_bfinal(const int* __restrict__ packed,
                                                const int* __restrict__ bbase,
                                                int* __restrict__ csr_src,
                                                int* __restrict__ rowptr,
                                                float* __restrict__ dinv) {
    __shared__ int pk[CAPE];
    __shared__ int outsrc[CAPE];
    __shared__ int hcnt[64], hoff[64], hcur[64];
    int b = blockIdx.x;
    int base = bbase[b];
    int cnt = bbase[b + 1] - base;
    if (cnt > CAPE) cnt = CAPE;  // statistically impossible; safety only
    int t = threadIdx.x;
    for (int i = t; i < cnt; i += 256) pk[i] = packed[base + i];
    if (t < 64) hcnt[t] = 0;
    __syncthreads();
    for (int i = t; i < cnt; i += 256) atomicAdd(&hcnt[pk[i] >> 16], 1);
    __syncthreads();
    if (t == 0) {
        int run = 0;
        for (int i = 0; i < 64; ++i) { hoff[i] = run; hcur[i] = run; run += hcnt[i]; }
    }
    __syncthreads();
    if (t < 64) {
        int node = b * 64 + t;
        if (node < NN) {
            rowptr[node] = base + hoff[t];
            dinv[node] = rsqrtf((float)(hcnt[t] + 1));
        }
    }
    for (int i = t; i < cnt; i += 256) {
        int lpos = atomicAdd(&hcur[pk[i] >> 16], 1);
        outsrc[lpos] = pk[i] & 0xFFFF;
    }
    __syncthreads();
    for (int i = t; i < cnt; i += 256) csr_src[base + i] = outsrc[i];
}

// ---------------- tiled fp32 GEMM: C[M][128] = A[M][K] @ B[K][128] ----------------
#define BM 64
#define BN 128
#define BK 16

__global__ __launch_bounds__(256) void k_gemm128(const float* __restrict__ A,
                                                 const float* __restrict__ B,
                                                 float* __restrict__ C,
                                                 int M, int K) {
    __shared__ float As[BM][BK + 4];
    __shared__ float Bs[BK][BN];
    const int tid = threadIdx.x;
    const int m0 = blockIdx.x * BM;
    const int tn = tid & 31;
    const int tm = tid >> 5;
    const int arow = tid >> 2;
    const int acol = (tid & 3) * 4;
    const int brow = tid >> 5;
    const int bcol = (tid & 31) * 4;

    float acc[8][4];
#pragma unroll
    for (int i = 0; i < 8; ++i)
#pragma unroll
        for (int j = 0; j < 4; ++j) acc[i][j] = 0.0f;

    for (int k0 = 0; k0 < K; k0 += BK) {
        int gm = m0 + arow;
        float4 av = make_float4(0.f, 0.f, 0.f, 0.f);
        if (gm < M) av = *(const float4*)(A + (size_t)gm * K + k0 + acol);
        *(float4*)(&As[arow][acol]) = av;
#pragma unroll
        for (int r = 0; r < 2; ++r) {
            int kk = brow + r * 8;
            float4 bv = *(const float4*)(B + (size_t)(k0 + kk) * BN + bcol);
            *(float4*)(&Bs[kk][bcol]) = bv;
        }
        __syncthreads();
#pragma unroll
        for (int kk = 0; kk < BK; ++kk) {
            float4 bv = *(const float4*)(&Bs[kk][tn * 4]);
            float b0 = bv.x, b1 = bv.y, b2 = bv.z, b3 = bv.w;
            float a[8];
#pragma unroll
            for (int i = 0; i < 8; ++i) a[i] = As[tm * 8 + i][kk];
#pragma unroll
            for (int i = 0; i < 8; ++i) {
                acc[i][0] = fmaf(a[i], b0, acc[i][0]);
                acc[i][1] = fmaf(a[i], b1, acc[i][1]);
                acc[i][2] = fmaf(a[i], b2, acc[i][2]);
                acc[i][3] = fmaf(a[i], b3, acc[i][3]);
            }
        }
        __syncthreads();
    }
#pragma unroll
    for (int i = 0; i < 8; ++i) {
        int gm = m0 + tm * 8 + i;
        if (gm < M) {
            float4 v = make_float4(acc[i][0], acc[i][1], acc[i][2], acc[i][3]);
            *(float4*)(C + (size_t)gm * BN + tn * 4) = v;
        }
    }
}

// ---------------- same GEMM but A-load applies BN(scale,shift)+ReLU per column k ----------------
__global__ __launch_bounds__(256) void k_gemm128_bn(const float* __restrict__ A,
                                                    const float* __restrict__ B,
                                                    const float* __restrict__ scsh,
                                                    float* __restrict__ C,
                                                    int M, int K) {
    __shared__ float As[BM][BK + 4];
    __shared__ float Bs[BK][BN];
    const float* sc = scsh;
    const float* sh = scsh + 128;
    const int tid = threadIdx.x;
    const int m0 = blockIdx.x * BM;
    const int tn = tid & 31;
    const int tm = tid >> 5;
    const int arow = tid >> 2;
    const int acol = (tid & 3) * 4;
    const int brow = tid >> 5;
    const int bcol = (tid & 31) * 4;

    float acc[8][4];
#pragma unroll
    for (int i = 0; i < 8; ++i)
#pragma unroll
        for (int j = 0; j < 4; ++j) acc[i][j] = 0.0f;

    for (int k0 = 0; k0 < K; k0 += BK) {
        int gm = m0 + arow;
        float4 av = make_float4(0.f, 0.f, 0.f, 0.f);
        if (gm < M) av = *(const float4*)(A + (size_t)gm * K + k0 + acol);
        float4 scv = *(const float4*)(sc + k0 + acol);
        float4 shv = *(const float4*)(sh + k0 + acol);
        av.x = fmaxf(fmaf(av.x, scv.x, shv.x), 0.0f);
        av.y = fmaxf(fmaf(av.y, scv.y, shv.y), 0.0f);
        av.z = fmaxf(fmaf(av.z, scv.z, shv.z), 0.0f);
        av.w = fmaxf(fmaf(av.w, scv.w, shv.w), 0.0f);
        *(float4*)(&As[arow][acol]) = av;
#pragma unroll
        for (int r = 0; r < 2; ++r) {
            int kk = brow + r * 8;
            float4 bv = *(const float4*)(B + (size_t)(k0 + kk) * BN + bcol);
            *(float4*)(&Bs[kk][bcol]) = bv;
        }
        __syncthreads();
#pragma unroll
        for (int kk = 0; kk < BK; ++kk) {
            float4 bv = *(const float4*)(&Bs[kk][tn * 4]);
            float b0 = bv.x, b1 = bv.y, b2 = bv.z, b3 = bv.w;
            float a[8];
#pragma unroll
            for (int i = 0; i < 8; ++i) a[i] = As[tm * 8 + i][kk];
#pragma unroll
            for (int i = 0; i < 8; ++i) {
                acc[i][0] = fmaf(a[i], b0, acc[i][0]);
                acc[i][1] = fmaf(a[i], b1, acc[i][1]);
                acc[i][2] = fmaf(a[i], b2, acc[i][2]);
                acc[i][3] = fmaf(a[i], b3, acc[i][3]);
            }
        }
        __syncthreads();
    }
#pragma unroll
    for (int i = 0; i < 8; ++i) {
        int gm = m0 + tm * 8 + i;
        if (gm < M) {
            float4 v = make_float4(acc[i][0], acc[i][1], acc[i][2], acc[i][3]);
            *(float4*)(C + (size_t)gm * BN + tn * 4) = v;
        }
    }
}

// ---------------- small GEMM with fused BN+ReLU: C[M][8] = relu(bn(A))[M][128] @ W[128][8] ----------------
__global__ __launch_bounds__(256) void k_gemm8_bn(const float* __restrict__ A,
                                                  const float* __restrict__ W,
                                                  const float* __restrict__ scsh,
                                                  float* __restrict__ C, int M) {
    __shared__ float Ws[128 * 8];
    __shared__ float scs[128], shs[128];
    int tid = threadIdx.x;
    for (int i = tid; i < 128 * 8; i += 256) Ws[i] = W[i];
    if (tid < 128) { scs[tid] = scsh[tid]; shs[tid] = scsh[tid + 128]; }
    __syncthreads();
    int m = blockIdx.x * 32 + (tid >> 3);
    int n = tid & 7;
    if (m >= M) return;
    const float* a = A + (size_t)m * 128;
    float s = 0.0f;
#pragma unroll
    for (int k = 0; k < 128; k += 4) {
        float4 av = *(const float4*)(a + k);
        float a0 = fmaxf(fmaf(av.x, scs[k + 0], shs[k + 0]), 0.0f);
        float a1 = fmaxf(fmaf(av.y, scs[k + 1], shs[k + 1]), 0.0f);
        float a2 = fmaxf(fmaf(av.z, scs[k + 2], shs[k + 2]), 0.0f);
        float a3 = fmaxf(fmaf(av.w, scs[k + 3], shs[k + 3]), 0.0f);
        s = fmaf(a0, Ws[(k + 0) * 8 + n], s);
        s = fmaf(a1, Ws[(k + 1) * 8 + n], s);
        s = fmaf(a2, Ws[(k + 2) * 8 + n], s);
        s = fmaf(a3, Ws[(k + 3) * 8 + n], s);
    }
    C[(size_t)m * 8 + n] = s;
}

// ---------------- CSR gather (128 cols): 32 lanes per node ----------------
__global__ __launch_bounds__(256) void k_gather128(const float* __restrict__ t,
                                                   const int* __restrict__ rowptr,
                                                   const int* __restrict__ csr_src,
                                                   const float* __restrict__ dinv,
                                                   const float* __restrict__ bias,
                                                   float* __restrict__ h) {
    int g = (blockIdx.x * 256 + threadIdx.x) >> 5;
    if (g >= NN) return;
    int c = (threadIdx.x & 31) * 4;
    int beg = rowptr[g], end = rowptr[g + 1];
    float dd = dinv[g];
    float4 sv = *(const float4*)(t + (size_t)g * 128 + c);
    float4 bv = *(const float4*)(bias + c);
    float wself = dd * dd;
    float ax = fmaf(sv.x, wself, bv.x);
    float ay = fmaf(sv.y, wself, bv.y);
    float az = fmaf(sv.z, wself, bv.z);
    float aw = fmaf(sv.w, wself, bv.w);
    int s = (beg < end) ? csr_src[beg] : 0;
    for (int e = beg; e < end; ++e) {
        int s_next = (e + 1 < end) ? csr_src[e + 1] : 0;
        float w = dinv[s] * dd;
        float4 v = *(const float4*)(t + (size_t)s * 128 + c);
        ax = fmaf(v.x, w, ax);
        ay = fmaf(v.y, w, ay);
        az = fmaf(v.z, w, az);
        aw = fmaf(v.w, w, aw);
        s = s_next;
    }
    float4 o = make_float4(ax, ay, az, aw);
    *(float4*)(h + (size_t)g * 128 + c) = o;
}

// ---------------- CSR gather (8 cols) + fused log_softmax ----------------
__global__ __launch_bounds__(256) void k_gather8_lsm(const float* __restrict__ t,
                                                     const int* __restrict__ rowptr,
                                                     const int* __restrict__ csr_src,
                                                     const float* __restrict__ dinv,
                                                     const float* __restrict__ bias,
                                                     float* __restrict__ out) {
    int g = (blockIdx.x * 256 + threadIdx.x) >> 3;
    if (g >= NN) return;
    int c = threadIdx.x & 7;
    int beg = rowptr[g], end = rowptr[g + 1];
    float dd = dinv[g];
    float acc = fmaf(t[(size_t)g * 8 + c], dd * dd, bias[c]);
    int s = (beg < end) ? csr_src[beg] : 0;
    for (int e = beg; e < end; ++e) {
        int s_next = (e + 1 < end) ? csr_src[e + 1] : 0;
        float w = dinv[s] * dd;
        acc = fmaf(t[(size_t)s * 8 + c], w, acc);
        s = s_next;
    }
    float mx = acc;
#pragma unroll
    for (int m = 1; m < 8; m <<= 1) mx = fmaxf(mx, __shfl_xor(mx, m, 8));
    float ex = expf(acc - mx);
    float se = ex;
#pragma unroll
    for (int m = 1; m < 8; m <<= 1) se += __shfl_xor(se, m, 8);
    out[(size_t)g * 8 + c] = acc - (logf(se) + mx);
}

// ---------------- BN stats (partial sums + atomics) ----------------
__global__ __launch_bounds__(256) void k_bnstats(const float* __restrict__ h,
                                                 float* __restrict__ sums,
                                                 float* __restrict__ sumsq) {
    int c4 = (threadIdx.x & 31) * 4;
    int rg = threadIdx.x >> 5;
    float s1x = 0, s1y = 0, s1z = 0, s1w = 0;
    float s2x = 0, s2y = 0, s2z = 0, s2w = 0;
    for (int r = blockIdx.x * 8 + rg; r < NN; r += gridDim.x * 8) {
        float4 v = *(const float4*)(h + (size_t)r * 128 + c4);
        s1x += v.x; s1y += v.y; s1z += v.z; s1w += v.w;
        s2x = fmaf(v.x, v.x, s2x);
        s2y = fmaf(v.y, v.y, s2y);
        s2z = fmaf(v.z, v.z, s2z);
        s2w = fmaf(v.w, v.w, s2w);
    }
    __shared__ float l1[256][4];
    __shared__ float l2[256][4];
    l1[threadIdx.x][0] = s1x; l1[threadIdx.x][1] = s1y;
    l1[threadIdx.x][2] = s1z; l1[threadIdx.x][3] = s1w;
    l2[threadIdx.x][0] = s2x; l2[threadIdx.x][1] = s2y;
    l2[threadIdx.x][2] = s2z; l2[threadIdx.x][3] = s2w;
    __syncthreads();
    if (rg == 0) {
        int lane = threadIdx.x & 31;
#pragma unroll
        for (int gg = 1; gg < 8; ++gg) {
            int o = gg * 32 + lane;
            s1x += l1[o][0]; s1y += l1[o][1]; s1z += l1[o][2]; s1w += l1[o][3];
            s2x += l2[o][0]; s2y += l2[o][1]; s2z += l2[o][2]; s2w += l2[o][3];
        }
        atomicAdd(&sums[c4 + 0], s1x);
        atomicAdd(&sums[c4 + 1], s1y);
        atomicAdd(&sums[c4 + 2], s1z);
        atomicAdd(&sums[c4 + 3], s1w);
        atomicAdd(&sumsq[c4 + 0], s2x);
        atomicAdd(&sumsq[c4 + 1], s2y);
        atomicAdd(&sumsq[c4 + 2], s2z);
        atomicAdd(&sumsq[c4 + 3], s2w);
    }
}

// ---------------- finalize BN: sums/sumsq -> scale/shift ----------------
__global__ void k_bnfin(const float* __restrict__ st, const float* __restrict__ g,
                        const float* __restrict__ beta, float* __restrict__ scsh) {
    int c = threadIdx.x;  // 128
    const float invn = 1.0f / (float)NN;
    float mu = st[c] * invn;
    float var = fmaf(-mu, mu, st[c + 128] * invn);
    float s = g[c] * rsqrtf(var + EPSBN);
    scsh[c] = s;
    scsh[c + 128] = fmaf(-mu, s, beta[c]);
}

extern "C" void kernel_launch(void* const* d_in, const int* in_sizes, int n_in,
                              void* d_out, int out_size, void* d_ws, size_t ws_size,
                              hipStream_t stream) {
    const float* x     = (const float*)d_in[0];
    const int*   eidx  = (const int*)d_in[1];
    const float* W1    = (const float*)d_in[2];
    const float* b1    = (const float*)d_in[3];
    const float* W2    = (const float*)d_in[4];
    const float* b2    = (const float*)d_in[5];
    const float* W3    = (const float*)d_in[6];
    const float* b3    = (const float*)d_in[7];
    const float* g1    = (const float*)d_in[8];
    const float* beta1 = (const float*)d_in[9];
    const float* g2    = (const float*)d_in[10];
    const float* beta2 = (const float*)d_in[11];
    float* out = (float*)d_out;

    const int* src = eidx;
    const int* dst = eidx + NE;

    char* ws = (char*)d_ws;
    int*   bcnt    = (int*)ws;          ws += NBP * 4;
    int*   bbase   = (int*)ws;          ws += NBP * 4;
    int*   bcursor = (int*)ws;          ws += NBP * 4;
    int*   rowptr  = (int*)ws;          ws += 51200 * 4;
    float* dinv    = (float*)ws;        ws += 51200 * 4;
    float* st      = (float*)ws;        ws += 512 * 4;       // st1 | st2
    float* scsh1   = (float*)ws;        ws += 256 * 4;
    float* scsh2   = (float*)ws;        ws += 256 * 4;
    int*   csr_src = (int*)ws;          ws += (size_t)NE * 4;
    float* A       = (float*)ws;        ws += (size_t)NN * 128 * 4;
    float* Bf      = (float*)ws;        ws += (size_t)NN * 128 * 4;
    float* C       = (float*)ws;
    int*   packed  = (int*)A;  // overlap: consumed by k_bfinal before gemm1 writes A

    // ---- CSR build (counting sort) + dinv ----
    k_zero<<<(NBP + 255) / 256, 256, 0, stream>>>(bcnt, st);
    k_bcount<<<(NE + 255) / 256, 256, 0, stream>>>(dst, bcnt);
    k_bscan<<<1, 1024, 0, stream>>>(bcnt, bbase, bcursor, rowptr);
    k_bscatter<<<(NE + 255) / 256, 256, 0, stream>>>(src, dst, bcursor, packed);
    k_bfinal<<<NB, 256, 0, stream>>>(packed, bbase, csr_src, rowptr, dinv);

    // ---- layer 1 ----
    k_gemm128<<<(NN + BM - 1) / BM, 256, 0, stream>>>(x, W1, A, NN, DIN);
    k_gather128<<<(NN * 32 + 255) / 256, 256, 0, stream>>>(A, rowptr, csr_src, dinv, b1, Bf);
    k_bnstats<<<512, 256, 0, stream>>>(Bf, st, st + 128);
    k_bnfin<<<1, 128, 0, stream>>>(st, g1, beta1, scsh1);

    // ---- layer 2 (BN1+ReLU fused into A-load) ----
    k_gemm128_bn<<<(NN + BM - 1) / BM, 256, 0, stream>>>(Bf, W2, scsh1, A, NN, HH);
    k_gather128<<<(NN * 32 + 255) / 256, 256, 0, stream>>>(A, rowptr, csr_src, dinv, b2, Bf);
    k_bnstats<<<512, 256, 0, stream>>>(Bf, st + 256, st + 384);
    k_bnfin<<<1, 128, 0, stream>>>(st + 256, g2, beta2, scsh2);

    // ---- layer 3 (BN2+ReLU fused into A-load) ----
    k_gemm8_bn<<<(NN + 31) / 32, 256, 0, stream>>>(Bf, W3, scsh2, C, NN);
    k_gather8_lsm<<<(NN * 8 + 255) / 256, 256, 0, stream>>>(C, rowptr, csr_src, dinv, b3, out);
}

// Round 6
// 648.532 us; speedup vs baseline: 1.9973x; 1.9973x over previous
//
#include <hip/hip_runtime.h>
#include <math.h>

#define NN 50000
#define NE 1600000
#define DIN 512
#define HH 128
#define EPSBN 1e-5f
#define NB 782        // ceil(NN/64) buckets of 64 nodes
#define PAD 16        // ints per bucket counter: one 64B line each (atomic serialization fix)
#define CAPE 4096     // per-bucket edge capacity (mean 2046)
#define CHUNK 6144    // edges per k_part block (24 per thread)
#define NBLK ((NE + CHUNK - 1) / CHUNK)

// ---------------- zero padded bucket counts + BN stat accumulators ----------------
__global__ void k_zero(int* __restrict__ bcnt, float* __restrict__ st) {
    int i = blockIdx.x * 256 + threadIdx.x;
    if (i < NB * PAD) bcnt[i] = 0;
    if (i < 512) st[i] = 0.0f;
}

// ---------------- bucket count (padded: 1 counter per 64B line) ----------------
__global__ void k_bcount(const int* __restrict__ dst, int* __restrict__ bcnt) {
    int e = blockIdx.x * 256 + threadIdx.x;
    if (e < NE) atomicAdd(&bcnt[(dst[e] >> 6) << 4], 1);
}

// ---------------- bucket scan (1 block, 1024 threads); bcnt becomes cursor ----------------
__global__ __launch_bounds__(1024) void k_bscan(int* __restrict__ bcnt,
                                                int* __restrict__ bbase,
                                                int* __restrict__ rowptr) {
    __shared__ int ps[1024];
    int t = threadIdx.x;
    int v = (t < NB) ? bcnt[t << 4] : 0;
    ps[t] = v;
    __syncthreads();
    for (int off = 1; off < 1024; off <<= 1) {
        int u = (t >= off) ? ps[t - off] : 0;
        __syncthreads();
        ps[t] += u;
        __syncthreads();
    }
    int ex = ps[t] - v;
    bbase[t] = ex;                 // t >= NB gets total (=NE), serves as bbase[NB]
    if (t < NB) bcnt[t << 4] = ex; // cursor init
    if (t == 0) rowptr[NN] = NE;   // sentinel: k_bfinal only writes node < NN  (round-5 bug)
}

// ---------------- LDS-staged multisplit: edges -> bucket-grouped packed array ----------------
// packed (UNSIGNED: b<<22 overflows int for b>=512!) = (bucket<<22) | (dst&63)<<16 | src
__global__ __launch_bounds__(256) void k_part(const int* __restrict__ src,
                                              const int* __restrict__ dst,
                                              int* __restrict__ bcursor,
                                              unsigned* __restrict__ packed) {
    __shared__ unsigned stage[CHUNK];
    __shared__ unsigned stage2[CHUNK];
    __shared__ int hist[1024];
    __shared__ int prefix[1024];
    __shared__ int baseg[1024];
    __shared__ int ps[256];
    int t = threadIdx.x;
    int eb = blockIdx.x * CHUNK;
    int cnt = NE - eb;
    if (cnt > CHUNK) cnt = CHUNK;

    for (int i = t; i < 1024; i += 256) hist[i] = 0;
    __syncthreads();
    for (int i = t; i < cnt; i += 256) {
        int e = eb + i;
        unsigned s = (unsigned)src[e];
        unsigned d = (unsigned)dst[e];
        unsigned b = d >> 6;
        stage[i] = (b << 22) | ((d & 63u) << 16) | s;
        atomicAdd(&hist[b], 1);
    }
    __syncthreads();
    // scan 1024 buckets with 256 threads (4 each)
    int b0 = t * 4;
    int h0 = hist[b0], h1 = hist[b0 + 1], h2 = hist[b0 + 2], h3 = hist[b0 + 3];
    int tot = h0 + h1 + h2 + h3;
    ps[t] = tot;
    __syncthreads();
    for (int off = 1; off < 256; off <<= 1) {
        int u = (t >= off) ? ps[t - off] : 0;
        __syncthreads();
        ps[t] += u;
        __syncthreads();
    }
    int ex = ps[t] - tot;
    prefix[b0] = ex;
    prefix[b0 + 1] = ex + h0;
    prefix[b0 + 2] = ex + h0 + h1;
    prefix[b0 + 3] = ex + h0 + h1 + h2;
    __syncthreads();
    // reserve global runs (one padded atomic per non-empty bucket), then hist -> cursor
    for (int b = t; b < 1024; b += 256) {
        int c = hist[b];
        if (c > 0 && b < NB) baseg[b] = atomicAdd(&bcursor[b << 4], c);
        hist[b] = prefix[b];
    }
    __syncthreads();
    // reorder into bucket-grouped stage2
    for (int i = t; i < cnt; i += 256) {
        unsigned pk = stage[i];
        int p = atomicAdd(&hist[pk >> 22], 1);
        stage2[p] = pk;
    }
    __syncthreads();
    // contiguous run writeout
    for (int i = t; i < cnt; i += 256) {
        unsigned pk = stage2[i];
        unsigned b = pk >> 22;
        packed[baseg[b] + (i - prefix[b])] = pk;
    }
}

// ---------------- per-bucket CSR finalize: csr_src, rowptr, dinv ----------------
__global__ __launch_bounds__(256) void k_bfinal(const unsigned* __restrict__ packed,
                                                const int* __restrict__ bbase,
                                                int* __restrict__ csr_src,
                                                int* __restrict__ rowptr,
                                                float* __restrict__ dinv) {
    __shared__ unsigned pk[CAPE];
    __shared__ int outsrc[CAPE];
    __shared__ int hcnt[64], hoff[64], hcur[64];
    int b = blockIdx.x;
    int base = bbase[b];
    int cnt = bbase[b + 1] - base;
    if (cnt > CAPE) cnt = CAPE;
    int t = threadIdx.x;
    for (int i = t; i < cnt; i += 256) pk[i] = packed[base + i];
    if (t < 64) hcnt[t] = 0;
    __syncthreads();
    for (int i = t; i < cnt; i += 256) atomicAdd(&hcnt[(pk[i] >> 16) & 63u], 1);
    __syncthreads();
    if (t == 0) {
        int run = 0;
        for (int i = 0; i < 64; ++i) { hoff[i] = run; hcur[i] = run; run += hcnt[i]; }
    }
    __syncthreads();
    if (t < 64) {
        int node = b * 64 + t;
        if (node < NN) {
            rowptr[node] = base + hoff[t];
            dinv[node] = rsqrtf((float)(hcnt[t] + 1));
        }
    }
    for (int i = t; i < cnt; i += 256) {
        int lpos = atomicAdd(&hcur[(pk[i] >> 16) & 63u], 1);
        outsrc[lpos] = (int)(pk[i] & 0xFFFFu);
    }
    __syncthreads();
    for (int i = t; i < cnt; i += 256) csr_src[base + i] = outsrc[i];
}

// ---------------- tiled fp32 GEMM: C[M][128] = A[M][K] @ B[K][128] ----------------
#define BM 64
#define BN 128
#define BK 16

__global__ __launch_bounds__(256) void k_gemm128(const float* __restrict__ A,
                                                 const float* __restrict__ B,
                                                 float* __restrict__ C,
                                                 int M, int K) {
    __shared__ float As[BM][BK + 4];
    __shared__ float Bs[BK][BN];
    const int tid = threadIdx.x;
    const int m0 = blockIdx.x * BM;
    const int tn = tid & 31;
    const int tm = tid >> 5;
    const int arow = tid >> 2;
    const int acol = (tid & 3) * 4;
    const int brow = tid >> 5;
    const int bcol = (tid & 31) * 4;

    float acc[8][4];
#pragma unroll
    for (int i = 0; i < 8; ++i)
#pragma unroll
        for (int j = 0; j < 4; ++j) acc[i][j] = 0.0f;

    for (int k0 = 0; k0 < K; k0 += BK) {
        int gm = m0 + arow;
        float4 av = make_float4(0.f, 0.f, 0.f, 0.f);
        if (gm < M) av = *(const float4*)(A + (size_t)gm * K + k0 + acol);
        *(float4*)(&As[arow][acol]) = av;
#pragma unroll
        for (int r = 0; r < 2; ++r) {
            int kk = brow + r * 8;
            float4 bv = *(const float4*)(B + (size_t)(k0 + kk) * BN + bcol);
            *(float4*)(&Bs[kk][bcol]) = bv;
        }
        __syncthreads();
#pragma unroll
        for (int kk = 0; kk < BK; ++kk) {
            float4 bv = *(const float4*)(&Bs[kk][tn * 4]);
            float b0 = bv.x, b1 = bv.y, b2 = bv.z, b3 = bv.w;
            float a[8];
#pragma unroll
            for (int i = 0; i < 8; ++i) a[i] = As[tm * 8 + i][kk];
#pragma unroll
            for (int i = 0; i < 8; ++i) {
                acc[i][0] = fmaf(a[i], b0, acc[i][0]);
                acc[i][1] = fmaf(a[i], b1, acc[i][1]);
                acc[i][2] = fmaf(a[i], b2, acc[i][2]);
                acc[i][3] = fmaf(a[i], b3, acc[i][3]);
            }
        }
        __syncthreads();
    }
#pragma unroll
    for (int i = 0; i < 8; ++i) {
        int gm = m0 + tm * 8 + i;
        if (gm < M) {
            float4 v = make_float4(acc[i][0], acc[i][1], acc[i][2], acc[i][3]);
            *(float4*)(C + (size_t)gm * BN + tn * 4) = v;
        }
    }
}

// ---------------- same GEMM, A-load applies BN(scale,shift)+ReLU per column k ----------------
__global__ __launch_bounds__(256) void k_gemm128_bn(const float* __restrict__ A,
                                                    const float* __restrict__ B,
                                                    const float* __restrict__ scsh,
                                                    float* __restrict__ C,
                                                    int M, int K) {
    __shared__ float As[BM][BK + 4];
    __shared__ float Bs[BK][BN];
    const float* sc = scsh;
    const float* sh = scsh + 128;
    const int tid = threadIdx.x;
    const int m0 = blockIdx.x * BM;
    const int tn = tid & 31;
    const int tm = tid >> 5;
    const int arow = tid >> 2;
    const int acol = (tid & 3) * 4;
    const int brow = tid >> 5;
    const int bcol = (tid & 31) * 4;

    float acc[8][4];
#pragma unroll
    for (int i = 0; i < 8; ++i)
#pragma unroll
        for (int j = 0; j < 4; ++j) acc[i][j] = 0.0f;

    for (int k0 = 0; k0 < K; k0 += BK) {
        int gm = m0 + arow;
        float4 av = make_float4(0.f, 0.f, 0.f, 0.f);
        if (gm < M) av = *(const float4*)(A + (size_t)gm * K + k0 + acol);
        float4 scv = *(const float4*)(sc + k0 + acol);
        float4 shv = *(const float4*)(sh + k0 + acol);
        av.x = fmaxf(fmaf(av.x, scv.x, shv.x), 0.0f);
        av.y = fmaxf(fmaf(av.y, scv.y, shv.y), 0.0f);
        av.z = fmaxf(fmaf(av.z, scv.z, shv.z), 0.0f);
        av.w = fmaxf(fmaf(av.w, scv.w, shv.w), 0.0f);
        *(float4*)(&As[arow][acol]) = av;
#pragma unroll
        for (int r = 0; r < 2; ++r) {
            int kk = brow + r * 8;
            float4 bv = *(const float4*)(B + (size_t)(k0 + kk) * BN + bcol);
            *(float4*)(&Bs[kk][bcol]) = bv;
        }
        __syncthreads();
#pragma unroll
        for (int kk = 0; kk < BK; ++kk) {
            float4 bv = *(const float4*)(&Bs[kk][tn * 4]);
            float b0 = bv.x, b1 = bv.y, b2 = bv.z, b3 = bv.w;
            float a[8];
#pragma unroll
            for (int i = 0; i < 8; ++i) a[i] = As[tm * 8 + i][kk];
#pragma unroll
            for (int i = 0; i < 8; ++i) {
                acc[i][0] = fmaf(a[i], b0, acc[i][0]);
                acc[i][1] = fmaf(a[i], b1, acc[i][1]);
                acc[i][2] = fmaf(a[i], b2, acc[i][2]);
                acc[i][3] = fmaf(a[i], b3, acc[i][3]);
            }
        }
        __syncthreads();
    }
#pragma unroll
    for (int i = 0; i < 8; ++i) {
        int gm = m0 + tm * 8 + i;
        if (gm < M) {
            float4 v = make_float4(acc[i][0], acc[i][1], acc[i][2], acc[i][3]);
            *(float4*)(C + (size_t)gm * BN + tn * 4) = v;
        }
    }
}

// ---------------- small GEMM with fused BN+ReLU: C[M][8] = relu(bn(A)) @ W[128][8] ----------------
__global__ __launch_bounds__(256) void k_gemm8_bn(const float* __restrict__ A,
                                                  const float* __restrict__ W,
                                                  const float* __restrict__ scsh,
                                                  float* __restrict__ C, int M) {
    __shared__ float Ws[128 * 8];
    __shared__ float scs[128], shs[128];
    int tid = threadIdx.x;
    for (int i = tid; i < 128 * 8; i += 256) Ws[i] = W[i];
    if (tid < 128) { scs[tid] = scsh[tid]; shs[tid] = scsh[tid + 128]; }
    __syncthreads();
    int m = blockIdx.x * 32 + (tid >> 3);
    int n = tid & 7;
    if (m >= M) return;
    const float* a = A + (size_t)m * 128;
    float s = 0.0f;
#pragma unroll
    for (int k = 0; k < 128; k += 4) {
        float4 av = *(const float4*)(a + k);
        float a0 = fmaxf(fmaf(av.x, scs[k + 0], shs[k + 0]), 0.0f);
        float a1 = fmaxf(fmaf(av.y, scs[k + 1], shs[k + 1]), 0.0f);
        float a2 = fmaxf(fmaf(av.z, scs[k + 2], shs[k + 2]), 0.0f);
        float a3 = fmaxf(fmaf(av.w, scs[k + 3], shs[k + 3]), 0.0f);
        s = fmaf(a0, Ws[(k + 0) * 8 + n], s);
        s = fmaf(a1, Ws[(k + 1) * 8 + n], s);
        s = fmaf(a2, Ws[(k + 2) * 8 + n], s);
        s = fmaf(a3, Ws[(k + 3) * 8 + n], s);
    }
    C[(size_t)m * 8 + n] = s;
}

// ---------------- CSR gather (128 cols): 32 lanes per node ----------------
__global__ __launch_bounds__(256) void k_gather128(const float* __restrict__ t,
                                                   const int* __restrict__ rowptr,
                                                   const int* __restrict__ csr_src,
                                                   const float* __restrict__ dinv,
                                                   const float* __restrict__ bias,
                                                   float* __restrict__ h) {
    int g = (blockIdx.x * 256 + threadIdx.x) >> 5;
    if (g >= NN) return;
    int c = (threadIdx.x & 31) * 4;
    int beg = rowptr[g], end = rowptr[g + 1];
    float dd = dinv[g];
    float4 sv = *(const float4*)(t + (size_t)g * 128 + c);
    float4 bv = *(const float4*)(bias + c);
    float wself = dd * dd;
    float ax = fmaf(sv.x, wself, bv.x);
    float ay = fmaf(sv.y, wself, bv.y);
    float az = fmaf(sv.z, wself, bv.z);
    float aw = fmaf(sv.w, wself, bv.w);
    int s = (beg < end) ? csr_src[beg] : 0;
    for (int e = beg; e < end; ++e) {
        int s_next = (e + 1 < end) ? csr_src[e + 1] : 0;
        float w = dinv[s] * dd;
        float4 v = *(const float4*)(t + (size_t)s * 128 + c);
        ax = fmaf(v.x, w, ax);
        ay = fmaf(v.y, w, ay);
        az = fmaf(v.z, w, az);
        aw = fmaf(v.w, w, aw);
        s = s_next;
    }
    float4 o = make_float4(ax, ay, az, aw);
    *(float4*)(h + (size_t)g * 128 + c) = o;
}

// ---------------- CSR gather (8 cols) + fused log_softmax ----------------
__global__ __launch_bounds__(256) void k_gather8_lsm(const float* __restrict__ t,
                                                     const int* __restrict__ rowptr,
                                                     const int* __restrict__ csr_src,
                                                     const float* __restrict__ dinv,
                                                     const float* __restrict__ bias,
                                                     float* __restrict__ out) {
    int g = (blockIdx.x * 256 + threadIdx.x) >> 3;
    if (g >= NN) return;
    int c = threadIdx.x & 7;
    int beg = rowptr[g], end = rowptr[g + 1];
    float dd = dinv[g];
    float acc = fmaf(t[(size_t)g * 8 + c], dd * dd, bias[c]);
    int s = (beg < end) ? csr_src[beg] : 0;
    for (int e = beg; e < end; ++e) {
        int s_next = (e + 1 < end) ? csr_src[e + 1] : 0;
        float w = dinv[s] * dd;
        acc = fmaf(t[(size_t)s * 8 + c], w, acc);
        s = s_next;
    }
    float mx = acc;
#pragma unroll
    for (int m = 1; m < 8; m <<= 1) mx = fmaxf(mx, __shfl_xor(mx, m, 8));
    float ex = expf(acc - mx);
    float se = ex;
#pragma unroll
    for (int m = 1; m < 8; m <<= 1) se += __shfl_xor(se, m, 8);
    out[(size_t)g * 8 + c] = acc - (logf(se) + mx);
}

// ---------------- BN stats (partial sums + atomics) ----------------
__global__ __launch_bounds__(256) void k_bnstats(const float* __restrict__ h,
                                                 float* __restrict__ sums,
                                                 float* __restrict__ sumsq) {
    int c4 = (threadIdx.x & 31) * 4;
    int rg = threadIdx.x >> 5;
    float s1x = 0, s1y = 0, s1z = 0, s1w = 0;
    float s2x = 0, s2y = 0, s2z = 0, s2w = 0;
    for (int r = blockIdx.x * 8 + rg; r < NN; r += gridDim.x * 8) {
        float4 v = *(const float4*)(h + (size_t)r * 128 + c4);
        s1x += v.x; s1y += v.y; s1z += v.z; s1w += v.w;
        s2x = fmaf(v.x, v.x, s2x);
        s2y = fmaf(v.y, v.y, s2y);
        s2z = fmaf(v.z, v.z, s2z);
        s2w = fmaf(v.w, v.w, s2w);
    }
    __shared__ float l1[256][4];
    __shared__ float l2[256][4];
    l1[threadIdx.x][0] = s1x; l1[threadIdx.x][1] = s1y;
    l1[threadIdx.x][2] = s1z; l1[threadIdx.x][3] = s1w;
    l2[threadIdx.x][0] = s2x; l2[threadIdx.x][1] = s2y;
    l2[threadIdx.x][2] = s2z; l2[threadIdx.x][3] = s2w;
    __syncthreads();
    if (rg == 0) {
        int lane = threadIdx.x & 31;
#pragma unroll
        for (int gg = 1; gg < 8; ++gg) {
            int o = gg * 32 + lane;
            s1x += l1[o][0]; s1y += l1[o][1]; s1z += l1[o][2]; s1w += l1[o][3];
            s2x += l2[o][0]; s2y += l2[o][1]; s2z += l2[o][2]; s2w += l2[o][3];
        }
        atomicAdd(&sums[c4 + 0], s1x);
        atomicAdd(&sums[c4 + 1], s1y);
        atomicAdd(&sums[c4 + 2], s1z);
        atomicAdd(&sums[c4 + 3], s1w);
        atomicAdd(&sumsq[c4 + 0], s2x);
        atomicAdd(&sumsq[c4 + 1], s2y);
        atomicAdd(&sumsq[c4 + 2], s2z);
        atomicAdd(&sumsq[c4 + 3], s2w);
    }
}

// ---------------- finalize BN: sums/sumsq -> scale/shift ----------------
__global__ void k_bnfin(const float* __restrict__ st, const float* __restrict__ g,
                        const float* __restrict__ beta, float* __restrict__ scsh) {
    int c = threadIdx.x;  // 128
    const float invn = 1.0f / (float)NN;
    float mu = st[c] * invn;
    float var = fmaf(-mu, mu, st[c + 128] * invn);
    float s = g[c] * rsqrtf(var + EPSBN);
    scsh[c] = s;
    scsh[c + 128] = fmaf(-mu, s, beta[c]);
}

extern "C" void kernel_launch(void* const* d_in, const int* in_sizes, int n_in,
                              void* d_out, int out_size, void* d_ws, size_t ws_size,
                              hipStream_t stream) {
    const float* x     = (const float*)d_in[0];
    const int*   eidx  = (const int*)d_in[1];
    const float* W1    = (const float*)d_in[2];
    const float* b1    = (const float*)d_in[3];
    const float* W2    = (const float*)d_in[4];
    const float* b2    = (const float*)d_in[5];
    const float* W3    = (const float*)d_in[6];
    const float* b3    = (const float*)d_in[7];
    const float* g1    = (const float*)d_in[8];
    const float* beta1 = (const float*)d_in[9];
    const float* g2    = (const float*)d_in[10];
    const float* beta2 = (const float*)d_in[11];
    float* out = (float*)d_out;

    const int* src = eidx;
    const int* dst = eidx + NE;

    char* ws = (char*)d_ws;
    int*   bcnt    = (int*)ws;          ws += 51200 * 4;   // padded counters (782*16) + slack
    int*   bbase   = (int*)ws;          ws += 2048 * 4;
    int*   rowptr  = (int*)ws;          ws += 51200 * 4;
    float* dinv    = (float*)ws;        ws += 51200 * 4;
    float* st      = (float*)ws;        ws += 512 * 4;     // st1 | st2
    float* scsh1   = (float*)ws;        ws += 256 * 4;
    float* scsh2   = (float*)ws;        ws += 256 * 4;
    int*   csr_src = (int*)ws;          ws += (size_t)NE * 4;
    float* A       = (float*)ws;        ws += (size_t)NN * 128 * 4;
    float* Bf      = (float*)ws;        ws += (size_t)NN * 128 * 4;
    float* C       = (float*)ws;
    unsigned* packed = (unsigned*)A;  // overlap: consumed by k_bfinal before gemm1 writes A

    // ---- CSR build: padded count -> scan -> LDS multisplit -> per-bucket finalize ----
    k_zero<<<(NB * PAD + 255) / 256, 256, 0, stream>>>(bcnt, st);
    k_bcount<<<(NE + 255) / 256, 256, 0, stream>>>(dst, bcnt);
    k_bscan<<<1, 1024, 0, stream>>>(bcnt, bbase, rowptr);
    k_part<<<NBLK, 256, 0, stream>>>(src, dst, bcnt, packed);
    k_bfinal<<<NB, 256, 0, stream>>>(packed, bbase, csr_src, rowptr, dinv);

    // ---- layer 1 ----
    k_gemm128<<<(NN + BM - 1) / BM, 256, 0, stream>>>(x, W1, A, NN, DIN);
    k_gather128<<<(NN * 32 + 255) / 256, 256, 0, stream>>>(A, rowptr, csr_src, dinv, b1, Bf);
    k_bnstats<<<512, 256, 0, stream>>>(Bf, st, st + 128);
    k_bnfin<<<1, 128, 0, stream>>>(st, g1, beta1, scsh1);

    // ---- layer 2 (BN1+ReLU fused into A-load) ----
    k_gemm128_bn<<<(NN + BM - 1) / BM, 256, 0, stream>>>(Bf, W2, scsh1, A, NN, HH);
    k_gather128<<<(NN * 32 + 255) / 256, 256, 0, stream>>>(A, rowptr, csr_src, dinv, b2, Bf);
    k_bnstats<<<512, 256, 0, stream>>>(Bf, st + 256, st + 384);
    k_bnfin<<<1, 128, 0, stream>>>(st + 256, g2, beta2, scsh2);

    // ---- layer 3 (BN2+ReLU fused into A-load) ----
    k_gemm8_bn<<<(NN + 31) / 32, 256, 0, stream>>>(Bf, W3, scsh2, C, NN);
    k_gather8_lsm<<<(NN * 8 + 255) / 256, 256, 0, stream>>>(C, rowptr, csr_src, dinv, b3, out);
}

// Round 7
// 523.573 us; speedup vs baseline: 2.4739x; 1.2387x over previous
//
#include <hip/hip_runtime.h>
#include <math.h>

#define NN 50000
#define NE 1600000
#define DIN 512
#define HH 128
#define EPSBN 1e-5f
#define NB 782        // ceil(NN/64) buckets of 64 nodes
#define PAD 16        // ints per bucket counter: one 64B line each
#define CAPE 4096     // per-bucket edge capacity (mean 2046)
#define CHUNK 6144    // edges per k_part block
#define NBLK ((NE + CHUNK - 1) / CHUNK)

typedef __attribute__((ext_vector_type(8))) short bf16x8;
typedef __attribute__((ext_vector_type(4))) float f32x4;

__device__ __forceinline__ unsigned short f2bf(float f) {
    unsigned u = __builtin_bit_cast(unsigned, f);
    u += 0x7FFFu + ((u >> 16) & 1u);   // RNE
    return (unsigned short)(u >> 16);
}
__device__ __forceinline__ unsigned packbf(float a, float b) {
    return (unsigned)f2bf(a) | ((unsigned)f2bf(b) << 16);
}
__device__ __forceinline__ float bf2f(unsigned short v) {
    return __builtin_bit_cast(float, (unsigned)v << 16);
}

// ---------------- zero padded bucket counts + BN stat accumulators ----------------
__global__ void k_zero(int* __restrict__ bcnt, float* __restrict__ st) {
    int i = blockIdx.x * 256 + threadIdx.x;
    if (i < NB * PAD) bcnt[i] = 0;
    if (i < 512) st[i] = 0.0f;
}

// ---------------- bucket count (padded: 1 counter per 64B line) ----------------
__global__ void k_bcount(const int* __restrict__ dst, int* __restrict__ bcnt) {
    int e = blockIdx.x * 256 + threadIdx.x;
    if (e < NE) atomicAdd(&bcnt[(dst[e] >> 6) << 4], 1);
}

// ---------------- bucket scan; bcnt becomes cursor ----------------
__global__ __launch_bounds__(1024) void k_bscan(int* __restrict__ bcnt,
                                                int* __restrict__ bbase,
                                                int* __restrict__ rowptr) {
    __shared__ int ps[1024];
    int t = threadIdx.x;
    int v = (t < NB) ? bcnt[t << 4] : 0;
    ps[t] = v;
    __syncthreads();
    for (int off = 1; off < 1024; off <<= 1) {
        int u = (t >= off) ? ps[t - off] : 0;
        __syncthreads();
        ps[t] += u;
        __syncthreads();
    }
    int ex = ps[t] - v;
    bbase[t] = ex;
    if (t < NB) bcnt[t << 4] = ex;
    if (t == 0) rowptr[NN] = NE;   // sentinel
}

// ---------------- LDS-staged multisplit (packed UNSIGNED: b<<22 | (dst&63)<<16 | src) ----------------
__global__ __launch_bounds__(256) void k_part(const int* __restrict__ src,
                                              const int* __restrict__ dst,
                                              int* __restrict__ bcursor,
                                              unsigned* __restrict__ packed) {
    __shared__ unsigned stage[CHUNK];
    __shared__ unsigned stage2[CHUNK];
    __shared__ int hist[1024];
    __shared__ int prefix[1024];
    __shared__ int baseg[1024];
    __shared__ int ps[256];
    int t = threadIdx.x;
    int eb = blockIdx.x * CHUNK;
    int cnt = NE - eb;
    if (cnt > CHUNK) cnt = CHUNK;

    for (int i = t; i < 1024; i += 256) hist[i] = 0;
    __syncthreads();
    for (int i = t; i < cnt; i += 256) {
        int e = eb + i;
        unsigned s = (unsigned)src[e];
        unsigned d = (unsigned)dst[e];
        unsigned b = d >> 6;
        stage[i] = (b << 22) | ((d & 63u) << 16) | s;
        atomicAdd(&hist[b], 1);
    }
    __syncthreads();
    int b0 = t * 4;
    int h0 = hist[b0], h1 = hist[b0 + 1], h2 = hist[b0 + 2], h3 = hist[b0 + 3];
    int tot = h0 + h1 + h2 + h3;
    ps[t] = tot;
    __syncthreads();
    for (int off = 1; off < 256; off <<= 1) {
        int u = (t >= off) ? ps[t - off] : 0;
        __syncthreads();
        ps[t] += u;
        __syncthreads();
    }
    int ex = ps[t] - tot;
    prefix[b0] = ex;
    prefix[b0 + 1] = ex + h0;
    prefix[b0 + 2] = ex + h0 + h1;
    prefix[b0 + 3] = ex + h0 + h1 + h2;
    __syncthreads();
    for (int b = t; b < 1024; b += 256) {
        int c = hist[b];
        if (c > 0 && b < NB) baseg[b] = atomicAdd(&bcursor[b << 4], c);
        hist[b] = prefix[b];
    }
    __syncthreads();
    for (int i = t; i < cnt; i += 256) {
        unsigned pk = stage[i];
        int p = atomicAdd(&hist[pk >> 22], 1);
        stage2[p] = pk;
    }
    __syncthreads();
    for (int i = t; i < cnt; i += 256) {
        unsigned pk = stage2[i];
        unsigned b = pk >> 22;
        packed[baseg[b] + (i - prefix[b])] = pk;
    }
}

// ---------------- per-bucket CSR finalize: csr_src, rowptr, dinv ----------------
__global__ __launch_bounds__(256) void k_bfinal(const unsigned* __restrict__ packed,
                                                const int* __restrict__ bbase,
                                                int* __restrict__ csr_src,
                                                int* __restrict__ rowptr,
                                                float* __restrict__ dinv) {
    __shared__ unsigned pk[CAPE];
    __shared__ int outsrc[CAPE];
    __shared__ int hcnt[64], hoff[64], hcur[64];
    int b = blockIdx.x;
    int base = bbase[b];
    int cnt = bbase[b + 1] - base;
    if (cnt > CAPE) cnt = CAPE;
    int t = threadIdx.x;
    for (int i = t; i < cnt; i += 256) pk[i] = packed[base + i];
    if (t < 64) hcnt[t] = 0;
    __syncthreads();
    for (int i = t; i < cnt; i += 256) atomicAdd(&hcnt[(pk[i] >> 16) & 63u], 1);
    __syncthreads();
    if (t == 0) {
        int run = 0;
        for (int i = 0; i < 64; ++i) { hoff[i] = run; hcur[i] = run; run += hcnt[i]; }
    }
    __syncthreads();
    if (t < 64) {
        int node = b * 64 + t;
        if (node < NN) {
            rowptr[node] = base + hoff[t];
            dinv[node] = rsqrtf((float)(hcnt[t] + 1));
        }
    }
    for (int i = t; i < cnt; i += 256) {
        int lpos = atomicAdd(&hcur[(pk[i] >> 16) & 63u], 1);
        outsrc[lpos] = (int)(pk[i] & 0xFFFFu);
    }
    __syncthreads();
    for (int i = t; i < cnt; i += 256) csr_src[base + i] = outsrc[i];
}

// ---------------- weight prep: W1[512][128],W2[128][128] f32 -> Wt[n][k] bf16 ----------------
__global__ void k_prepw(const float* __restrict__ W1, const float* __restrict__ W2,
                        unsigned short* __restrict__ W1t, unsigned short* __restrict__ W2t) {
    int i = blockIdx.x * 256 + threadIdx.x;
    if (i < 512 * 128) {
        int k = i >> 7, n = i & 127;
        W1t[n * 512 + k] = f2bf(W1[i]);
    }
    if (i < 128 * 128) {
        int k = i >> 7, n = i & 127;
        W2t[n * 128 + k] = f2bf(W2[i]);
    }
}

// ---------------- MFMA GEMM: Cb[M][128](bf16) = [bn/relu](A[M][K] f32) @ Wt^T ----------------
// Wt is bf16 [128][K] (row n = column n of W). Tile 64x128, K-chunk 64, 4 waves.
__global__ __launch_bounds__(256) void k_gemm_mfma(const float* __restrict__ A,
                                                   const unsigned short* __restrict__ Wt,
                                                   const float* __restrict__ scsh,
                                                   int apply_bn,
                                                   unsigned short* __restrict__ Cb,
                                                   int M, int K) {
    __shared__ unsigned short As[64][72];   // +8 pad: 2-way bank aliasing (free)
    __shared__ unsigned short Bs[128][72];
    const int tid = threadIdx.x;
    const int m0 = blockIdx.x * 64;
    const int w = tid >> 6;
    const int lane = tid & 63;
    const int cr = lane & 15;
    const int half = lane >> 4;

    const int arow = tid >> 2;          // 0..63
    const int akseg = (tid & 3) << 4;   // 0,16,32,48
    const int brow = tid >> 1;          // 0..127
    const int bkseg = (tid & 1) << 5;   // 0,32

    f32x4 acc[8];
#pragma unroll
    for (int n = 0; n < 8; ++n) acc[n] = (f32x4){0.f, 0.f, 0.f, 0.f};

    for (int kc = 0; kc < K; kc += 64) {
        // ---- stage A: fp32 -> (BN+ReLU) -> bf16 ----
        float4 va[4];
        int gm = m0 + arow;
        if (gm < M) {
            const float* ap = A + (size_t)gm * K + kc + akseg;
#pragma unroll
            for (int i = 0; i < 4; ++i) va[i] = ((const float4*)ap)[i];
        } else {
#pragma unroll
            for (int i = 0; i < 4; ++i) va[i] = make_float4(0.f, 0.f, 0.f, 0.f);
        }
        if (apply_bn) {
#pragma unroll
            for (int i = 0; i < 4; ++i) {
                int k = kc + akseg + i * 4;
                float4 scv = *(const float4*)(scsh + k);
                float4 shv = *(const float4*)(scsh + 128 + k);
                va[i].x = fmaxf(fmaf(va[i].x, scv.x, shv.x), 0.f);
                va[i].y = fmaxf(fmaf(va[i].y, scv.y, shv.y), 0.f);
                va[i].z = fmaxf(fmaf(va[i].z, scv.z, shv.z), 0.f);
                va[i].w = fmaxf(fmaf(va[i].w, scv.w, shv.w), 0.f);
            }
        }
        uint4 q0, q1;
        q0.x = packbf(va[0].x, va[0].y); q0.y = packbf(va[0].z, va[0].w);
        q0.z = packbf(va[1].x, va[1].y); q0.w = packbf(va[1].z, va[1].w);
        q1.x = packbf(va[2].x, va[2].y); q1.y = packbf(va[2].z, va[2].w);
        q1.z = packbf(va[3].x, va[3].y); q1.w = packbf(va[3].z, va[3].w);
        *(uint4*)(&As[arow][akseg]) = q0;
        *(uint4*)(&As[arow][akseg + 8]) = q1;

        // ---- stage B: bf16 copy (already [n][k] in global) ----
        {
            const unsigned short* wp = Wt + (size_t)brow * K + kc + bkseg;
            uint4* bp = (uint4*)(&Bs[brow][bkseg]);
#pragma unroll
            for (int i = 0; i < 4; ++i) bp[i] = ((const uint4*)wp)[i];
        }
        __syncthreads();

        const int wrow = w << 4;
#pragma unroll
        for (int ks = 0; ks < 2; ++ks) {
            bf16x8 af = *(const bf16x8*)(&As[wrow + cr][ks * 32 + half * 8]);
#pragma unroll
            for (int n = 0; n < 8; ++n) {
                bf16x8 bfr = *(const bf16x8*)(&Bs[n * 16 + cr][ks * 32 + half * 8]);
                acc[n] = __builtin_amdgcn_mfma_f32_16x16x32_bf16(af, bfr, acc[n], 0, 0, 0);
            }
        }
        __syncthreads();
    }

    // ---- epilogue: D col=lane&15, row=(lane>>4)*4+reg ----
#pragma unroll
    for (int n = 0; n < 8; ++n) {
#pragma unroll
        for (int reg = 0; reg < 4; ++reg) {
            int gr = m0 + (w << 4) + half * 4 + reg;
            if (gr < M) Cb[(size_t)gr * 128 + n * 16 + cr] = f2bf(acc[n][reg]);
        }
    }
}

// ---------------- CSR gather (128 cols, bf16 table): 32 lanes per node ----------------
__global__ __launch_bounds__(256) void k_gather128(const unsigned short* __restrict__ t,
                                                   const int* __restrict__ rowptr,
                                                   const int* __restrict__ csr_src,
                                                   const float* __restrict__ dinv,
                                                   const float* __restrict__ bias,
                                                   float* __restrict__ h) {
    int g = (blockIdx.x * 256 + threadIdx.x) >> 5;
    if (g >= NN) return;
    int c = (threadIdx.x & 31) * 4;
    int beg = rowptr[g], end = rowptr[g + 1];
    float dd = dinv[g];
    ushort4 sv = *(const ushort4*)(t + (size_t)g * 128 + c);
    float4 bv = *(const float4*)(bias + c);
    float wself = dd * dd;
    float ax = fmaf(bf2f(sv.x), wself, bv.x);
    float ay = fmaf(bf2f(sv.y), wself, bv.y);
    float az = fmaf(bf2f(sv.z), wself, bv.z);
    float aw = fmaf(bf2f(sv.w), wself, bv.w);
    int s = (beg < end) ? csr_src[beg] : 0;
    for (int e = beg; e < end; ++e) {
        int s_next = (e + 1 < end) ? csr_src[e + 1] : 0;
        float w = dinv[s] * dd;
        ushort4 v = *(const ushort4*)(t + (size_t)s * 128 + c);
        ax = fmaf(bf2f(v.x), w, ax);
        ay = fmaf(bf2f(v.y), w, ay);
        az = fmaf(bf2f(v.z), w, az);
        aw = fmaf(bf2f(v.w), w, aw);
        s = s_next;
    }
    float4 o = make_float4(ax, ay, az, aw);
    *(float4*)(h + (size_t)g * 128 + c) = o;
}

// ---------------- small GEMM with fused BN+ReLU: C[M][8] = relu(bn(A)) @ W[128][8] ----------------
__global__ __launch_bounds__(256) void k_gemm8_bn(const float* __restrict__ A,
                                                  const float* __restrict__ W,
                                                  const float* __restrict__ scsh,
                                                  float* __restrict__ C, int M) {
    __shared__ float Ws[128 * 8];
    __shared__ float scs[128], shs[128];
    int tid = threadIdx.x;
    for (int i = tid; i < 128 * 8; i += 256) Ws[i] = W[i];
    if (tid < 128) { scs[tid] = scsh[tid]; shs[tid] = scsh[tid + 128]; }
    __syncthreads();
    int m = blockIdx.x * 32 + (tid >> 3);
    int n = tid & 7;
    if (m >= M) return;
    const float* a = A + (size_t)m * 128;
    float s = 0.0f;
#pragma unroll
    for (int k = 0; k < 128; k += 4) {
        float4 av = *(const float4*)(a + k);
        float a0 = fmaxf(fmaf(av.x, scs[k + 0], shs[k + 0]), 0.0f);
        float a1 = fmaxf(fmaf(av.y, scs[k + 1], shs[k + 1]), 0.0f);
        float a2 = fmaxf(fmaf(av.z, scs[k + 2], shs[k + 2]), 0.0f);
        float a3 = fmaxf(fmaf(av.w, scs[k + 3], shs[k + 3]), 0.0f);
        s = fmaf(a0, Ws[(k + 0) * 8 + n], s);
        s = fmaf(a1, Ws[(k + 1) * 8 + n], s);
        s = fmaf(a2, Ws[(k + 2) * 8 + n], s);
        s = fmaf(a3, Ws[(k + 3) * 8 + n], s);
    }
    C[(size_t)m * 8 + n] = s;
}

// ---------------- CSR gather (8 cols) + fused log_softmax ----------------
__global__ __launch_bounds__(256) void k_gather8_lsm(const float* __restrict__ t,
                                                     const int* __restrict__ rowptr,
                                                     const int* __restrict__ csr_src,
                                                     const float* __restrict__ dinv,
                                                     const float* __restrict__ bias,
                                                     float* __restrict__ out) {
    int g = (blockIdx.x * 256 + threadIdx.x) >> 3;
    if (g >= NN) return;
    int c = threadIdx.x & 7;
    int beg = rowptr[g], end = rowptr[g + 1];
    float dd = dinv[g];
    float acc = fmaf(t[(size_t)g * 8 + c], dd * dd, bias[c]);
    int s = (beg < end) ? csr_src[beg] : 0;
    for (int e = beg; e < end; ++e) {
        int s_next = (e + 1 < end) ? csr_src[e + 1] : 0;
        float w = dinv[s] * dd;
        acc = fmaf(t[(size_t)s * 8 + c], w, acc);
        s = s_next;
    }
    float mx = acc;
#pragma unroll
    for (int m = 1; m < 8; m <<= 1) mx = fmaxf(mx, __shfl_xor(mx, m, 8));
    float ex = expf(acc - mx);
    float se = ex;
#pragma unroll
    for (int m = 1; m < 8; m <<= 1) se += __shfl_xor(se, m, 8);
    out[(size_t)g * 8 + c] = acc - (logf(se) + mx);
}

// ---------------- BN stats (partial sums + atomics) ----------------
__global__ __launch_bounds__(256) void k_bnstats(const float* __restrict__ h,
                                                 float* __restrict__ sums,
                                                 float* __restrict__ sumsq) {
    int c4 = (threadIdx.x & 31) * 4;
    int rg = threadIdx.x >> 5;
    float s1x = 0, s1y = 0, s1z = 0, s1w = 0;
    float s2x = 0, s2y = 0, s2z = 0, s2w = 0;
    for (int r = blockIdx.x * 8 + rg; r < NN; r += gridDim.x * 8) {
        float4 v = *(const float4*)(h + (size_t)r * 128 + c4);
        s1x += v.x; s1y += v.y; s1z += v.z; s1w += v.w;
        s2x = fmaf(v.x, v.x, s2x);
        s2y = fmaf(v.y, v.y, s2y);
        s2z = fmaf(v.z, v.z, s2z);
        s2w = fmaf(v.w, v.w, s2w);
    }
    __shared__ float l1[256][4];
    __shared__ float l2[256][4];
    l1[threadIdx.x][0] = s1x; l1[threadIdx.x][1] = s1y;
    l1[threadIdx.x][2] = s1z; l1[threadIdx.x][3] = s1w;
    l2[threadIdx.x][0] = s2x; l2[threadIdx.x][1] = s2y;
    l2[threadIdx.x][2] = s2z; l2[threadIdx.x][3] = s2w;
    __syncthreads();
    if (rg == 0) {
        int lane = threadIdx.x & 31;
#pragma unroll
        for (int gg = 1; gg < 8; ++gg) {
            int o = gg * 32 + lane;
            s1x += l1[o][0]; s1y += l1[o][1]; s1z += l1[o][2]; s1w += l1[o][3];
            s2x += l2[o][0]; s2y += l2[o][1]; s2z += l2[o][2]; s2w += l2[o][3];
        }
        atomicAdd(&sums[c4 + 0], s1x);
        atomicAdd(&sums[c4 + 1], s1y);
        atomicAdd(&sums[c4 + 2], s1z);
        atomicAdd(&sums[c4 + 3], s1w);
        atomicAdd(&sumsq[c4 + 0], s2x);
        atomicAdd(&sumsq[c4 + 1], s2y);
        atomicAdd(&sumsq[c4 + 2], s2z);
        atomicAdd(&sumsq[c4 + 3], s2w);
    }
}

// ---------------- finalize BN: sums/sumsq -> scale/shift ----------------
__global__ void k_bnfin(const float* __restrict__ st, const float* __restrict__ g,
                        const float* __restrict__ beta, float* __restrict__ scsh) {
    int c = threadIdx.x;  // 128
    const float invn = 1.0f / (float)NN;
    float mu = st[c] * invn;
    float var = fmaf(-mu, mu, st[c + 128] * invn);
    float s = g[c] * rsqrtf(var + EPSBN);
    scsh[c] = s;
    scsh[c + 128] = fmaf(-mu, s, beta[c]);
}

extern "C" void kernel_launch(void* const* d_in, const int* in_sizes, int n_in,
                              void* d_out, int out_size, void* d_ws, size_t ws_size,
                              hipStream_t stream) {
    const float* x     = (const float*)d_in[0];
    const int*   eidx  = (const int*)d_in[1];
    const float* W1    = (const float*)d_in[2];
    const float* b1    = (const float*)d_in[3];
    const float* W2    = (const float*)d_in[4];
    const float* b2    = (const float*)d_in[5];
    const float* W3    = (const float*)d_in[6];
    const float* b3    = (const float*)d_in[7];
    const float* g1    = (const float*)d_in[8];
    const float* beta1 = (const float*)d_in[9];
    const float* g2    = (const float*)d_in[10];
    const float* beta2 = (const float*)d_in[11];
    float* out = (float*)d_out;

    const int* src = eidx;
    const int* dst = eidx + NE;

    char* ws = (char*)d_ws;
    int*   bcnt    = (int*)ws;            ws += 51200 * 4;
    int*   bbase   = (int*)ws;            ws += 2048 * 4;
    int*   rowptr  = (int*)ws;            ws += 51200 * 4;
    float* dinv    = (float*)ws;          ws += 51200 * 4;
    float* st      = (float*)ws;          ws += 512 * 4;     // st1 | st2
    float* scsh1   = (float*)ws;          ws += 256 * 4;
    float* scsh2   = (float*)ws;          ws += 256 * 4;
    int*   csr_src = (int*)ws;            ws += (size_t)NE * 4;
    unsigned short* W1t = (unsigned short*)ws;  ws += 128 * 512 * 2;
    unsigned short* W2t = (unsigned short*)ws;  ws += 128 * 128 * 2;
    unsigned short* Ab  = (unsigned short*)ws;  ws += (size_t)50048 * 128 * 2;  // bf16 gemm out
    float* Bf      = (float*)ws;          ws += (size_t)NN * 128 * 4;
    float* C       = (float*)ws;
    unsigned* packed = (unsigned*)Ab;  // overlap: consumed by k_bfinal before gemm1 writes Ab

    // ---- CSR build: padded count -> scan -> LDS multisplit -> per-bucket finalize ----
    k_zero<<<(NB * PAD + 255) / 256, 256, 0, stream>>>(bcnt, st);
    k_bcount<<<(NE + 255) / 256, 256, 0, stream>>>(dst, bcnt);
    k_bscan<<<1, 1024, 0, stream>>>(bcnt, bbase, rowptr);
    k_part<<<NBLK, 256, 0, stream>>>(src, dst, bcnt, packed);
    k_bfinal<<<NB, 256, 0, stream>>>(packed, bbase, csr_src, rowptr, dinv);
    k_prepw<<<256, 256, 0, stream>>>(W1, W2, W1t, W2t);

    // ---- layer 1 (bf16 MFMA GEMM, no BN) ----
    k_gemm_mfma<<<(NN + 63) / 64, 256, 0, stream>>>(x, W1t, scsh1, 0, Ab, NN, DIN);
    k_gather128<<<(NN * 32 + 255) / 256, 256, 0, stream>>>(Ab, rowptr, csr_src, dinv, b1, Bf);
    k_bnstats<<<512, 256, 0, stream>>>(Bf, st, st + 128);
    k_bnfin<<<1, 128, 0, stream>>>(st, g1, beta1, scsh1);

    // ---- layer 2 (BN1+ReLU fused into A-staging of MFMA GEMM) ----
    k_gemm_mfma<<<(NN + 63) / 64, 256, 0, stream>>>(Bf, W2t, scsh1, 1, Ab, NN, HH);
    k_gather128<<<(NN * 32 + 255) / 256, 256, 0, stream>>>(Ab, rowptr, csr_src, dinv, b2, Bf);
    k_bnstats<<<512, 256, 0, stream>>>(Bf, st + 256, st + 384);
    k_bnfin<<<1, 128, 0, stream>>>(st + 256, g2, beta2, scsh2);

    // ---- layer 3 (BN2+ReLU fused into A-load) ----
    k_gemm8_bn<<<(NN + 31) / 32, 256, 0, stream>>>(Bf, W3, scsh2, C, NN);
    k_gather8_lsm<<<(NN * 8 + 255) / 256, 256, 0, stream>>>(C, rowptr, csr_src, dinv, b3, out);
}